// Round 1
// baseline (8305.762 us; speedup 1.0000x reference)
//
#include <hip/hip_runtime.h>

#define BB 512
#define TT 256
#define FDIM 128
#define HDIM 512
#define FFD 1024
#define OUTD 64
#define PADV -999.0f
#define NBLK 256
#define NTHR 256

typedef __bf16 bf16_t;
typedef bf16_t bf16x8 __attribute__((ext_vector_type(8)));
typedef float f32x4 __attribute__((ext_vector_type(4)));

// LDS: role-specialized weight slabs (resident across all 256 time steps).
// Pitches padded (+8 elems) so 16-lane column-strided b128 reads are 2-way
// bank aliased (free on CDNA4, m136).
union LdsU {
  struct {                      // A-role (GRU gates), 128 blocks
    bf16_t rz[64 * 648];        // [r|z] slab, K=640 concat [x|h], col-major
    bf16_t nh[32 * 520];        // h_n slab, K=512 (h only)
    bf16_t ni[32 * 136];        // i_n slab, K=128 (x only)
    float  ex[4][64][33];       // gate exchange: [r,z,nh,ni][row][col] (+1 pad)
  } a;
  struct {                      // B-role (FF1) + C-addon (FF2), 128 blocks
    bf16_t w1[64 * 520];        // W1 slab, K=512
    bf16_t w2[16 * 1032];       // W2 slab, K=1024
  } b;
};

__device__ __forceinline__ f32x4 mfma16(bf16x8 a, bf16x8 b, f32x4 c) {
  return __builtin_amdgcn_mfma_f32_16x16x32_bf16(a, b, c, 0, 0, 0);
}
__device__ __forceinline__ float sigm(float x) { return 1.f / (1.f + __expf(-x)); }
__device__ __forceinline__ float tanh_f(float x) { return 2.f / (1.f + __expf(-2.f * x)) - 1.f; }

__global__ __launch_bounds__(NTHR) void gru_net_kernel(
    const float* __restrict__ x, const int* __restrict__ seq,
    const float* __restrict__ Wih, const float* __restrict__ Whh,
    const float* __restrict__ bih, const float* __restrict__ bhh,
    const float* __restrict__ W1, const float* __restrict__ b1,
    const float* __restrict__ W2, const float* __restrict__ b2,
    float* __restrict__ out,
    bf16_t* __restrict__ hb, bf16_t* __restrict__ ff, bf16_t* __restrict__ hd,
    unsigned* __restrict__ bar) {
  __shared__ LdsU L;
  __shared__ float biasA[4][32];   // [b_r, b_z, b_in, b_hn] for block's 32 h-cols
  __shared__ float b1s[64];
  __shared__ float b2s[16];
  __shared__ int   seqA[64];
  __shared__ int   seqC[64];

  const int blk = blockIdx.x, tid = threadIdx.x;
  const int wv = tid >> 6, lane = tid & 63;
  const int q = lane >> 4, col16 = lane & 15, q8 = q * 8;
  const bool isA = blk < 128;

  // ---- preamble: zero h_{-1} buffer (hb[1]) ----
  {
    uint4* hz = (uint4*)(hb + (size_t)BB * HDIM);
    const int nz = BB * HDIM * 2 / 16;
    uint4 z; z.x = z.y = z.z = z.w = 0u;
    for (int idx = blk * NTHR + tid; idx < nz; idx += NBLK * NTHR) hz[idx] = z;
  }

  int b0 = 0, c0 = 0, f0 = 0, b0c = 0, o0 = 0;
  bool hasC = false;
  if (isA) {
    b0 = (blk >> 4) * 64;          // batch row group (8)
    c0 = (blk & 15) * 32;          // h-col group (16)
    { // rz slab: cols 0..31 = r (Wih/Whh rows c0+cj), 32..63 = z (rows 512+...)
      const int cj = tid & 63, kq = tid >> 6;
      const int g = (cj < 32) ? (c0 + cj) : (512 + c0 + (cj - 32));
      for (int kk = 0; kk < 160; ++kk) {
        const int k = kq * 160 + kk;
        const float w = (k < 128) ? Wih[g * FDIM + k]
                                  : Whh[(size_t)g * HDIM + (k - 128)];
        L.a.rz[cj * 648 + k] = (bf16_t)w;
      }
    }
    { // nh (K=512) and ni (K=128) slabs: n-gate rows 1024+c0+cj
      const int cj = tid & 31, kq = tid >> 5;
      const int g = 1024 + c0 + cj;
      for (int kk = 0; kk < 64; ++kk) {
        const int k = kq * 64 + kk;
        L.a.nh[cj * 520 + k] = (bf16_t)Whh[(size_t)g * HDIM + k];
      }
      for (int kk = 0; kk < 16; ++kk) {
        const int k = kq * 16 + kk;
        L.a.ni[cj * 136 + k] = (bf16_t)Wih[g * FDIM + k];
      }
    }
    if (tid < 32) {
      biasA[0][tid] = bih[c0 + tid] + bhh[c0 + tid];
      biasA[1][tid] = bih[512 + c0 + tid] + bhh[512 + c0 + tid];
      biasA[2][tid] = bih[1024 + c0 + tid];   // i_n bias
      biasA[3][tid] = bhh[1024 + c0 + tid];   // h_n bias
    }
    if (tid < 64) seqA[tid] = seq[b0 + tid];
  } else {
    const int cidx = blk - 128;
    b0 = (cidx >> 4) * 64;
    f0 = (cidx & 15) * 64;
    { // W1 slab, coalesced over f
      const int fj = tid & 63, kq = tid >> 6;
      for (int kk = 0; kk < 128; ++kk) {
        const int k = kq + kk * 4;
        L.b.w1[fj * 520 + k] = (bf16_t)W1[(size_t)k * FFD + f0 + fj];
      }
    }
    if (tid < 64) b1s[tid] = b1[f0 + tid];
    hasC = (cidx < 32);
    if (hasC) {
      b0c = (cidx >> 2) * 64;
      o0 = (cidx & 3) * 16;
      const int oj = tid & 15, kq = tid >> 4;
      for (int kk = 0; kk < 64; ++kk) {
        const int k = kq * 64 + kk;
        L.b.w2[oj * 1032 + k] = (bf16_t)W2[k * OUTD + o0 + oj];
      }
      if (tid < 16) b2s[tid] = b2[o0 + tid];
      if (tid < 64) seqC[tid] = seq[b0c + tid];
    }
  }

  // ---- pipelined time loop: iter i does A(t=i), B(t=i-1), C(t=i-2) ----
  unsigned tgt = NBLK;
  for (int it = 0; it < TT + 2; ++it, tgt += NBLK) {
    // grid barrier (monotonic counter, device scope, sense-free)
    __syncthreads();
    if (tid == 0) {
      __threadfence();             // agent release: flush block's dirty lines
      atomicAdd(bar, 1u);
      while (__hip_atomic_load(bar, __ATOMIC_RELAXED, __HIP_MEMORY_SCOPE_AGENT) < tgt) {
        __builtin_amdgcn_s_sleep(1);
      }
      __threadfence();             // agent acquire: invalidate stale lines
    }
    __syncthreads();

    if (isA) {
      if (it < TT) {
        const int t = it;
        const bf16_t* hr = hb + (size_t)((t + 1) & 1) * BB * HDIM;
        bf16_t* hw = hb + (size_t)(t & 1) * BB * HDIM;
        bf16_t* fw = ff + (size_t)(t & 1) * BB * HDIM;
        const int rA = b0 + wv * 16 + col16;
        const float*  paxf = x + ((size_t)rA * TT + t) * FDIM;
        const bf16_t* pah  = hr + (size_t)rA * HDIM;
        const f32x4 zz = {0.f, 0.f, 0.f, 0.f};
        f32x4 acc[4] = {zz, zz, zz, zz};
        f32x4 accn[2] = {zz, zz};
        f32x4 acci[2] = {zz, zz};
        // x part: K 0..127 feeds rz (k<128) and ni
        #pragma unroll
        for (int ks = 0; ks < 4; ++ks) {
          const int ko = ks * 32 + q8;
          const float4 u0 = *(const float4*)(paxf + ko);
          const float4 u1 = *(const float4*)(paxf + ko + 4);
          bf16x8 av;
          av[0]=(bf16_t)u0.x; av[1]=(bf16_t)u0.y; av[2]=(bf16_t)u0.z; av[3]=(bf16_t)u0.w;
          av[4]=(bf16_t)u1.x; av[5]=(bf16_t)u1.y; av[6]=(bf16_t)u1.z; av[7]=(bf16_t)u1.w;
          #pragma unroll
          for (int j = 0; j < 4; ++j) {
            const bf16x8 bv = *(const bf16x8*)&L.a.rz[(j * 16 + col16) * 648 + ko];
            acc[j] = mfma16(av, bv, acc[j]);
          }
          #pragma unroll
          for (int j = 0; j < 2; ++j) {
            const bf16x8 bv = *(const bf16x8*)&L.a.ni[(j * 16 + col16) * 136 + ko];
            acci[j] = mfma16(av, bv, acci[j]);
          }
        }
        // h part: K 0..511 feeds rz (k>=128) and nh; one a-frag load, 6 MFMAs
        #pragma unroll 2
        for (int ks = 0; ks < 16; ++ks) {
          const int ko = ks * 32 + q8;
          const bf16x8 av = *(const bf16x8*)(pah + ko);
          #pragma unroll
          for (int j = 0; j < 4; ++j) {
            const bf16x8 bv = *(const bf16x8*)&L.a.rz[(j * 16 + col16) * 648 + 128 + ko];
            acc[j] = mfma16(av, bv, acc[j]);
          }
          #pragma unroll
          for (int j = 0; j < 2; ++j) {
            const bf16x8 bv = *(const bf16x8*)&L.a.nh[(j * 16 + col16) * 520 + ko];
            accn[j] = mfma16(av, bv, accn[j]);
          }
        }
        // dump gate sums to LDS exchange (C/D: col=lane&15, row=q*4+reg)
        #pragma unroll
        for (int j = 0; j < 4; ++j) {
          const int sl = j >> 1, cb = (j & 1) * 16 + col16;
          #pragma unroll
          for (int rg = 0; rg < 4; ++rg)
            L.a.ex[sl][wv * 16 + q * 4 + rg][cb] = acc[j][rg];
        }
        #pragma unroll
        for (int j = 0; j < 2; ++j) {
          const int cb = j * 16 + col16;
          #pragma unroll
          for (int rg = 0; rg < 4; ++rg) {
            L.a.ex[2][wv * 16 + q * 4 + rg][cb] = accn[j][rg];
            L.a.ex[3][wv * 16 + q * 4 + rg][cb] = acci[j][rg];
          }
        }
        __syncthreads();
        // elementwise GRU update for the block's 64x32 h-tile
        for (int e = tid; e < 64 * 32; e += NTHR) {
          const int row = e >> 5, c = e & 31;
          const int bidx = b0 + row;
          const float gr  = L.a.ex[0][row][c] + biasA[0][c];
          const float gz  = L.a.ex[1][row][c] + biasA[1][c];
          const float gnh = L.a.ex[2][row][c] + biasA[3][c];
          const float gni = L.a.ex[3][row][c] + biasA[2][c];
          const float r = sigm(gr), zg = sigm(gz);
          const float n = tanh_f(gni + r * gnh);
          const float hp = (float)hr[(size_t)bidx * HDIM + c0 + c];
          const float hnew = (1.f - zg) * n + zg * hp;
          const bool v = (t < seqA[row]);
          hw[(size_t)bidx * HDIM + c0 + c] = (bf16_t)(v ? hnew : hp);
          fw[(size_t)bidx * HDIM + c0 + c] = (bf16_t)(v ? hnew : 0.f);
        }
      }
    } else {
      if (it >= 1 && it <= TT) {           // FF1 for t = it-1
        const int t = it - 1;
        const bf16_t* fr = ff + (size_t)(t & 1) * BB * HDIM;
        bf16_t* hwid = hd + (size_t)(t & 1) * BB * FFD;
        const int rB = b0 + wv * 16 + col16;
        const bf16_t* pa = fr + (size_t)rB * HDIM;
        const f32x4 zz = {0.f, 0.f, 0.f, 0.f};
        f32x4 acc[4] = {zz, zz, zz, zz};
        #pragma unroll 4
        for (int ks = 0; ks < 16; ++ks) {
          const int ko = ks * 32 + q8;
          const bf16x8 av = *(const bf16x8*)(pa + ko);
          #pragma unroll
          for (int j = 0; j < 4; ++j) {
            const bf16x8 bv = *(const bf16x8*)&L.b.w1[(j * 16 + col16) * 520 + ko];
            acc[j] = mfma16(av, bv, acc[j]);
          }
        }
        #pragma unroll
        for (int j = 0; j < 4; ++j) {
          const int fc = j * 16 + col16;
          #pragma unroll
          for (int rg = 0; rg < 4; ++rg) {
            const int rb = b0 + wv * 16 + q * 4 + rg;
            const float v = acc[j][rg] + b1s[fc];
            hwid[(size_t)rb * FFD + f0 + fc] = (bf16_t)fmaxf(v, 0.f);
          }
        }
      }
      if (hasC && it >= 2) {               // FF2 for t = it-2
        const int t = it - 2;
        const bf16_t* hr2 = hd + (size_t)(t & 1) * BB * FFD;
        const int rC = b0c + wv * 16 + col16;
        const bf16_t* pa = hr2 + (size_t)rC * FFD;
        f32x4 acc = {0.f, 0.f, 0.f, 0.f};
        #pragma unroll 4
        for (int ks = 0; ks < 32; ++ks) {
          const int ko = ks * 32 + q8;
          const bf16x8 av = *(const bf16x8*)(pa + ko);
          const bf16x8 bv = *(const bf16x8*)&L.b.w2[col16 * 1032 + ko];
          acc = mfma16(av, bv, acc);
        }
        #pragma unroll
        for (int rg = 0; rg < 4; ++rg) {
          const int lr = wv * 16 + q * 4 + rg;
          const int rb = b0c + lr;
          const float v = acc[rg] + b2s[col16];
          out[((size_t)rb * TT + t) * OUTD + o0 + col16] = (t < seqC[lr]) ? v : PADV;
        }
      }
    }
  }
}

extern "C" void kernel_launch(void* const* d_in, const int* in_sizes, int n_in,
                              void* d_out, int out_size, void* d_ws, size_t ws_size,
                              hipStream_t stream) {
  const float* x   = (const float*)d_in[0];
  const int*   seq = (const int*)d_in[1];
  const float* Wih = (const float*)d_in[2];
  const float* Whh = (const float*)d_in[3];
  const float* bih = (const float*)d_in[4];
  const float* bhh = (const float*)d_in[5];
  const float* W1  = (const float*)d_in[6];
  const float* b1  = (const float*)d_in[7];
  const float* W2  = (const float*)d_in[8];
  const float* b2  = (const float*)d_in[9];
  float* out = (float*)d_out;
  char* ws = (char*)d_ws;

  unsigned* bar = (unsigned*)ws;                       // barrier counter
  bf16_t* hb = (bf16_t*)(ws + 256);                    // h ping-pong  2*B*H
  bf16_t* ff = hb + (size_t)2 * BB * HDIM;             // ffin ping-pong
  bf16_t* hd = ff + (size_t)2 * BB * HDIM;             // hid ping-pong 2*B*FF
  // total scratch ~4.2 MB

  hipMemsetAsync(ws, 0, 256, stream);
  void* args[] = {&x, &seq, &Wih, &Whh, &bih, &bhh, &W1, &b1, &W2, &b2,
                  &out, &hb, &ff, &hd, &bar};
  hipLaunchCooperativeKernel((void*)gru_net_kernel, dim3(NBLK), dim3(NTHR),
                             args, 0, stream);
}

// Round 5
// 7723.683 us; speedup vs baseline: 1.0754x; 1.0754x over previous
//
#include <hip/hip_runtime.h>

#define BB 512
#define TT 256
#define FDIM 128
#define HDIM 512
#define FFD 1024
#define OUTD 64
#define PADV -999.0f
#define NBLK 256
#define NTHR 256

typedef __bf16 bf16_t;
typedef bf16_t bf16x8 __attribute__((ext_vector_type(8)));
typedef float f32x4 __attribute__((ext_vector_type(4)));

// LDS: role-specialized weight slabs (resident across all 256 time steps).
// Pitches padded (+8 elems) so 16-lane column-strided b128 reads are 2-way
// bank aliased (free on CDNA4, m136).
union LdsU {
  struct {                      // A-role (GRU gates), 128 blocks
    bf16_t rz[64 * 648];        // [r|z] slab, K=640 concat [x|h], col-major
    bf16_t nh[32 * 520];        // h_n slab, K=512 (h only)
    bf16_t ni[32 * 136];        // i_n slab, K=128 (x only)
    float  ex[4][64][33];       // gate exchange: [r,z,nh,ni][row][col] (+1 pad)
  } a;
  struct {                      // B-role (FF1) + C-addon (FF2), 128 blocks
    bf16_t w1[64 * 520];        // W1 slab, K=512
    bf16_t w2[16 * 1032];       // W2 slab, K=1024
  } b;
};

__device__ __forceinline__ f32x4 mfma16(bf16x8 a, bf16x8 b, f32x4 c) {
  return __builtin_amdgcn_mfma_f32_16x16x32_bf16(a, b, c, 0, 0, 0);
}
__device__ __forceinline__ float sigm(float x) { return 1.f / (1.f + __expf(-x)); }
__device__ __forceinline__ float tanh_f(float x) { return 2.f / (1.f + __expf(-2.f * x)) - 1.f; }

__global__ __launch_bounds__(NTHR) void gru_net_kernel(
    const float* __restrict__ x, const int* __restrict__ seq,
    const float* __restrict__ Wih, const float* __restrict__ Whh,
    const float* __restrict__ bih, const float* __restrict__ bhh,
    const float* __restrict__ W1, const float* __restrict__ b1,
    const float* __restrict__ W2, const float* __restrict__ b2,
    float* __restrict__ out,
    bf16_t* __restrict__ hb, bf16_t* __restrict__ ff, bf16_t* __restrict__ hd,
    unsigned* __restrict__ bar) {
  __shared__ LdsU L;
  __shared__ float biasA[4][32];   // [b_r, b_z, b_in, b_hn] for block's 32 h-cols
  __shared__ float b1s[64];
  __shared__ float b2s[16];
  __shared__ int   seqA[64];
  __shared__ int   seqC[64];

  const int blk = blockIdx.x, tid = threadIdx.x;
  const int wv = tid >> 6, lane = tid & 63;
  const int q = lane >> 4, col16 = lane & 15, q8 = q * 8;
  const bool isA = blk < 128;

  // ---- preamble: zero h_{-1} buffer (hb[1]) ----
  {
    uint4* hz = (uint4*)(hb + (size_t)BB * HDIM);
    const int nz = BB * HDIM * 2 / 16;
    uint4 z; z.x = z.y = z.z = z.w = 0u;
    for (int idx = blk * NTHR + tid; idx < nz; idx += NBLK * NTHR) hz[idx] = z;
  }

  // XCD-locality remap: batch-group = blk%8 so (with round-robin blk->XCD
  // dispatch) each group's A producers and B/C consumers share one XCD L2;
  // the post-barrier L2 refill then fetches each line once, not 8x.
  int b0 = 0, c0 = 0, f0 = 0, b0c = 0, o0 = 0;
  bool hasC = false;
  if (isA) {
    b0 = (blk & 7) * 64;           // batch row group (8)
    c0 = (blk >> 3) * 32;          // h-col group (16)
    { // rz slab: cols 0..31 = r (Wih/Whh rows c0+cj), 32..63 = z (rows 512+...)
      const int cj = tid & 63, kq = tid >> 6;
      const int g = (cj < 32) ? (c0 + cj) : (512 + c0 + (cj - 32));
      for (int kk = 0; kk < 160; ++kk) {
        const int k = kq * 160 + kk;
        const float w = (k < 128) ? Wih[g * FDIM + k]
                                  : Whh[(size_t)g * HDIM + (k - 128)];
        L.a.rz[cj * 648 + k] = (bf16_t)w;
      }
    }
    { // nh (K=512) and ni (K=128) slabs: n-gate rows 1024+c0+cj
      const int cj = tid & 31, kq = tid >> 5;
      const int g = 1024 + c0 + cj;
      for (int kk = 0; kk < 64; ++kk) {
        const int k = kq * 64 + kk;
        L.a.nh[cj * 520 + k] = (bf16_t)Whh[(size_t)g * HDIM + k];
      }
      for (int kk = 0; kk < 16; ++kk) {
        const int k = kq * 16 + kk;
        L.a.ni[cj * 136 + k] = (bf16_t)Wih[g * FDIM + k];
      }
    }
    if (tid < 32) {
      biasA[0][tid] = bih[c0 + tid] + bhh[c0 + tid];
      biasA[1][tid] = bih[512 + c0 + tid] + bhh[512 + c0 + tid];
      biasA[2][tid] = bih[1024 + c0 + tid];   // i_n bias
      biasA[3][tid] = bhh[1024 + c0 + tid];   // h_n bias
    }
    if (tid < 64) seqA[tid] = seq[b0 + tid];
  } else {
    const int cidx = blk - 128;
    b0 = (cidx & 7) * 64;          // batch group (same XCD residue as A of g)
    f0 = (cidx >> 3) * 64;         // FF col group (16)
    { // W1 slab, coalesced over f
      const int fj = tid & 63, kq = tid >> 6;
      for (int kk = 0; kk < 128; ++kk) {
        const int k = kq + kk * 4;
        L.b.w1[fj * 520 + k] = (bf16_t)W1[(size_t)k * FFD + f0 + fj];
      }
    }
    if (tid < 64) b1s[tid] = b1[f0 + tid];
    hasC = (cidx < 32);
    if (hasC) {
      b0c = (cidx & 7) * 64;       // batch group (same XCD residue)
      o0 = (cidx >> 3) * 16;       // out col group (4)
      const int oj = tid & 15, kq = tid >> 4;
      for (int kk = 0; kk < 64; ++kk) {
        const int k = kq * 64 + kk;
        L.b.w2[oj * 1032 + k] = (bf16_t)W2[k * OUTD + o0 + oj];
      }
      if (tid < 16) b2s[tid] = b2[o0 + tid];
      if (tid < 64) seqC[tid] = seq[b0c + tid];
    }
  }

  // ---- pipelined time loop: iter i does A(t=i), B(t=i-1), C(t=i-2) ----
  unsigned tgt = NBLK;
  for (int it = 0; it < TT + 2; ++it, tgt += NBLK) {
    // grid barrier (monotonic counter, device scope, sense-free)
    __syncthreads();
    if (tid == 0) {
      __threadfence();             // agent release: flush block's dirty lines
      atomicAdd(bar, 1u);
      while (__hip_atomic_load(bar, __ATOMIC_RELAXED, __HIP_MEMORY_SCOPE_AGENT) < tgt) {
        __builtin_amdgcn_s_sleep(1);
      }
      __threadfence();             // agent acquire: invalidate stale lines
    }
    __syncthreads();

    if (isA) {
      if (it < TT) {
        const int t = it;
        const bf16_t* hr = hb + (size_t)((t + 1) & 1) * BB * HDIM;
        bf16_t* hw = hb + (size_t)(t & 1) * BB * HDIM;
        bf16_t* fw = ff + (size_t)(t & 1) * BB * HDIM;
        const int rA = b0 + wv * 16 + col16;
        const float*  paxf = x + ((size_t)rA * TT + t) * FDIM;
        const bf16_t* pah  = hr + (size_t)rA * HDIM;
        const f32x4 zz = {0.f, 0.f, 0.f, 0.f};
        f32x4 acc[4] = {zz, zz, zz, zz};
        f32x4 accn[2] = {zz, zz};
        f32x4 acci[2] = {zz, zz};
        // x part: K 0..127 feeds rz (k<128) and ni
        #pragma unroll
        for (int ks = 0; ks < 4; ++ks) {
          const int ko = ks * 32 + q8;
          const float4 u0 = *(const float4*)(paxf + ko);
          const float4 u1 = *(const float4*)(paxf + ko + 4);
          bf16x8 av;
          av[0]=(bf16_t)u0.x; av[1]=(bf16_t)u0.y; av[2]=(bf16_t)u0.z; av[3]=(bf16_t)u0.w;
          av[4]=(bf16_t)u1.x; av[5]=(bf16_t)u1.y; av[6]=(bf16_t)u1.z; av[7]=(bf16_t)u1.w;
          #pragma unroll
          for (int j = 0; j < 4; ++j) {
            const bf16x8 bv = *(const bf16x8*)&L.a.rz[(j * 16 + col16) * 648 + ko];
            acc[j] = mfma16(av, bv, acc[j]);
          }
          #pragma unroll
          for (int j = 0; j < 2; ++j) {
            const bf16x8 bv = *(const bf16x8*)&L.a.ni[(j * 16 + col16) * 136 + ko];
            acci[j] = mfma16(av, bv, acci[j]);
          }
        }
        // h part: K 0..511 feeds rz (k>=128) and nh; one a-frag load, 6 MFMAs
        #pragma unroll 2
        for (int ks = 0; ks < 16; ++ks) {
          const int ko = ks * 32 + q8;
          const bf16x8 av = *(const bf16x8*)(pah + ko);
          #pragma unroll
          for (int j = 0; j < 4; ++j) {
            const bf16x8 bv = *(const bf16x8*)&L.a.rz[(j * 16 + col16) * 648 + 128 + ko];
            acc[j] = mfma16(av, bv, acc[j]);
          }
          #pragma unroll
          for (int j = 0; j < 2; ++j) {
            const bf16x8 bv = *(const bf16x8*)&L.a.nh[(j * 16 + col16) * 520 + ko];
            accn[j] = mfma16(av, bv, accn[j]);
          }
        }
        // dump gate sums to LDS exchange (C/D: col=lane&15, row=q*4+reg)
        #pragma unroll
        for (int j = 0; j < 4; ++j) {
          const int sl = j >> 1, cb = (j & 1) * 16 + col16;
          #pragma unroll
          for (int rg = 0; rg < 4; ++rg)
            L.a.ex[sl][wv * 16 + q * 4 + rg][cb] = acc[j][rg];
        }
        #pragma unroll
        for (int j = 0; j < 2; ++j) {
          const int cb = j * 16 + col16;
          #pragma unroll
          for (int rg = 0; rg < 4; ++rg) {
            L.a.ex[2][wv * 16 + q * 4 + rg][cb] = accn[j][rg];
            L.a.ex[3][wv * 16 + q * 4 + rg][cb] = acci[j][rg];
          }
        }
        __syncthreads();
        // elementwise GRU update for the block's 64x32 h-tile
        for (int e = tid; e < 64 * 32; e += NTHR) {
          const int row = e >> 5, c = e & 31;
          const int bidx = b0 + row;
          const float gr  = L.a.ex[0][row][c] + biasA[0][c];
          const float gz  = L.a.ex[1][row][c] + biasA[1][c];
          const float gnh = L.a.ex[2][row][c] + biasA[3][c];
          const float gni = L.a.ex[3][row][c] + biasA[2][c];
          const float r = sigm(gr), zg = sigm(gz);
          const float n = tanh_f(gni + r * gnh);
          const float hp = (float)hr[(size_t)bidx * HDIM + c0 + c];
          const float hnew = (1.f - zg) * n + zg * hp;
          const bool v = (t < seqA[row]);
          hw[(size_t)bidx * HDIM + c0 + c] = (bf16_t)(v ? hnew : hp);
          fw[(size_t)bidx * HDIM + c0 + c] = (bf16_t)(v ? hnew : 0.f);
        }
      }
    } else {
      if (it >= 1 && it <= TT) {           // FF1 for t = it-1
        const int t = it - 1;
        const bf16_t* fr = ff + (size_t)(t & 1) * BB * HDIM;
        bf16_t* hwid = hd + (size_t)(t & 1) * BB * FFD;
        const int rB = b0 + wv * 16 + col16;
        const bf16_t* pa = fr + (size_t)rB * HDIM;
        const f32x4 zz = {0.f, 0.f, 0.f, 0.f};
        f32x4 acc[4] = {zz, zz, zz, zz};
        #pragma unroll 4
        for (int ks = 0; ks < 16; ++ks) {
          const int ko = ks * 32 + q8;
          const bf16x8 av = *(const bf16x8*)(pa + ko);
          #pragma unroll
          for (int j = 0; j < 4; ++j) {
            const bf16x8 bv = *(const bf16x8*)&L.b.w1[(j * 16 + col16) * 520 + ko];
            acc[j] = mfma16(av, bv, acc[j]);
          }
        }
        #pragma unroll
        for (int j = 0; j < 4; ++j) {
          const int fc = j * 16 + col16;
          #pragma unroll
          for (int rg = 0; rg < 4; ++rg) {
            const int rb = b0 + wv * 16 + q * 4 + rg;
            const float v = acc[j][rg] + b1s[fc];
            hwid[(size_t)rb * FFD + f0 + fc] = (bf16_t)fmaxf(v, 0.f);
          }
        }
      }
      if (hasC && it >= 2) {               // FF2 for t = it-2
        const int t = it - 2;
        const bf16_t* hr2 = hd + (size_t)(t & 1) * BB * FFD;
        const int rC = b0c + wv * 16 + col16;
        const bf16_t* pa = hr2 + (size_t)rC * FFD;
        f32x4 acc = {0.f, 0.f, 0.f, 0.f};
        #pragma unroll 4
        for (int ks = 0; ks < 32; ++ks) {
          const int ko = ks * 32 + q8;
          const bf16x8 av = *(const bf16x8*)(pa + ko);
          const bf16x8 bv = *(const bf16x8*)&L.b.w2[col16 * 1032 + ko];
          acc = mfma16(av, bv, acc);
        }
        #pragma unroll
        for (int rg = 0; rg < 4; ++rg) {
          const int lr = wv * 16 + q * 4 + rg;
          const int rb = b0c + lr;
          const float v = acc[rg] + b2s[col16];
          out[((size_t)rb * TT + t) * OUTD + o0 + col16] = (t < seqC[lr]) ? v : PADV;
        }
      }
    }
  }
}

extern "C" void kernel_launch(void* const* d_in, const int* in_sizes, int n_in,
                              void* d_out, int out_size, void* d_ws, size_t ws_size,
                              hipStream_t stream) {
  const float* x   = (const float*)d_in[0];
  const int*   seq = (const int*)d_in[1];
  const float* Wih = (const float*)d_in[2];
  const float* Whh = (const float*)d_in[3];
  const float* bih = (const float*)d_in[4];
  const float* bhh = (const float*)d_in[5];
  const float* W1  = (const float*)d_in[6];
  const float* b1  = (const float*)d_in[7];
  const float* W2  = (const float*)d_in[8];
  const float* b2  = (const float*)d_in[9];
  float* out = (float*)d_out;
  char* ws = (char*)d_ws;

  unsigned* bar = (unsigned*)ws;                       // barrier counter
  bf16_t* hb = (bf16_t*)(ws + 256);                    // h ping-pong  2*B*H
  bf16_t* ff = hb + (size_t)2 * BB * HDIM;             // ffin ping-pong
  bf16_t* hd = ff + (size_t)2 * BB * HDIM;             // hid ping-pong 2*B*FF
  // total scratch ~4.2 MB

  hipMemsetAsync(ws, 0, 256, stream);
  void* args[] = {&x, &seq, &Wih, &Whh, &bih, &bhh, &W1, &b1, &W2, &b2,
                  &out, &hb, &ff, &hd, &bar};
  hipLaunchCooperativeKernel((void*)gru_net_kernel, dim3(NBLK), dim3(NTHR),
                             args, 0, stream);
}

// Round 7
// 4863.963 us; speedup vs baseline: 1.7076x; 1.5879x over previous
//
#include <hip/hip_runtime.h>

#define BB 512
#define TT 256
#define FDIM 128
#define HDIM 512
#define FFD 1024
#define OUTD 64
#define PADV -999.0f
#define NBLK 256
#define NTHR 256

typedef __bf16 bf16_t;
typedef bf16_t bf16x8 __attribute__((ext_vector_type(8)));
typedef float f32x4 __attribute__((ext_vector_type(4)));
typedef unsigned long long u64;

// LDS: role-specialized weight slabs (resident across all 256 time steps).
union LdsU {
  struct {                      // A-role (GRU gates), 128 blocks
    bf16_t rz[64 * 648];        // [r|z] slab, K=640 concat [x|h], col-major
    bf16_t nh[32 * 520];        // h_n slab, K=512 (h only)
    bf16_t ni[32 * 136];        // i_n slab, K=128 (x only)
    float  ex[4][64][33];       // gate exchange: [r,z,nh,ni][row][col] (+1 pad)
  } a;
  struct {                      // B-role (FF1) + C-addon (FF2), 128 blocks
    bf16_t w1[64 * 520];        // W1 slab, K=512
    bf16_t w2[16 * 1032];       // W2 slab, K=1024
    bf16_t st[64 * 72];         // FF1 output restage for contiguous 8B stores
  } b;
};

__device__ __forceinline__ f32x4 mfma16(bf16x8 a, bf16x8 b, f32x4 c) {
  return __builtin_amdgcn_mfma_f32_16x16x32_bf16(a, b, c, 0, 0, 0);
}
__device__ __forceinline__ float sigm(float x) { return 1.f / (1.f + __expf(-x)); }
__device__ __forceinline__ float tanh_f(float x) { return 2.f / (1.f + __expf(-2.f * x)) - 1.f; }

// NOTE: __hip_atomic_* pointers must be NON-CONST (const-qualified pointer
// args fail to compile; this was the R2/R3/R4/R6 stub-failure cause).

__global__ __launch_bounds__(NTHR) void gru_net_kernel(
    const float* __restrict__ x, const int* __restrict__ seq,
    const float* __restrict__ Wih, const float* __restrict__ Whh,
    const float* __restrict__ bih, const float* __restrict__ bhh,
    const float* __restrict__ W1, const float* __restrict__ b1,
    const float* __restrict__ W2, const float* __restrict__ b2,
    float* __restrict__ out,
    bf16_t* __restrict__ hb, bf16_t* __restrict__ ff, bf16_t* __restrict__ hd,
    unsigned* __restrict__ bar) {
  __shared__ LdsU L;
  __shared__ float biasA[4][32];   // [b_r, b_z, b_in, b_hn] for block's 32 h-cols
  __shared__ float b1s[64];
  __shared__ float b2s[16];
  __shared__ int   seqA[64];
  __shared__ int   seqC[64];

  const int blk = blockIdx.x, tid = threadIdx.x;
  const int wv = tid >> 6, lane = tid & 63;
  const int q = lane >> 4, col16 = lane & 15, q8 = q * 8;
  const bool isA = blk < 128;

  // ---- preamble: zero h_{-1} buffer (hb[1]) via L3-coherent stores ----
  {
    u64* hz = (u64*)(hb + (size_t)BB * HDIM);
    const int nz = BB * HDIM / 4;
    for (int idx = blk * NTHR + tid; idx < nz; idx += NBLK * NTHR)
      __hip_atomic_store(hz + idx, 0ull, __ATOMIC_RELAXED, __HIP_MEMORY_SCOPE_AGENT);
  }

  // XCD-locality remap: batch-group = blk%8 so (with round-robin blk->XCD
  // dispatch) each group's A producers and B/C consumers share one XCD L2.
  int b0 = 0, c0 = 0, f0 = 0, b0c = 0, o0 = 0;
  bool hasC = false;
  if (isA) {
    b0 = (blk & 7) * 64;           // batch row group (8)
    c0 = (blk >> 3) * 32;          // h-col group (16)
    { // rz slab: cols 0..31 = r (Wih/Whh rows c0+cj), 32..63 = z (rows 512+...)
      const int cj = tid & 63, kq = tid >> 6;
      const int g = (cj < 32) ? (c0 + cj) : (512 + c0 + (cj - 32));
      for (int kk = 0; kk < 160; ++kk) {
        const int k = kq * 160 + kk;
        const float w = (k < 128) ? Wih[g * FDIM + k]
                                  : Whh[(size_t)g * HDIM + (k - 128)];
        L.a.rz[cj * 648 + k] = (bf16_t)w;
      }
    }
    { // nh (K=512) and ni (K=128) slabs: n-gate rows 1024+c0+cj
      const int cj = tid & 31, kq = tid >> 5;
      const int g = 1024 + c0 + cj;
      for (int kk = 0; kk < 64; ++kk) {
        const int k = kq * 64 + kk;
        L.a.nh[cj * 520 + k] = (bf16_t)Whh[(size_t)g * HDIM + k];
      }
      for (int kk = 0; kk < 16; ++kk) {
        const int k = kq * 16 + kk;
        L.a.ni[cj * 136 + k] = (bf16_t)Wih[g * FDIM + k];
      }
    }
    if (tid < 32) {
      biasA[0][tid] = bih[c0 + tid] + bhh[c0 + tid];
      biasA[1][tid] = bih[512 + c0 + tid] + bhh[512 + c0 + tid];
      biasA[2][tid] = bih[1024 + c0 + tid];   // i_n bias
      biasA[3][tid] = bhh[1024 + c0 + tid];   // h_n bias
    }
    if (tid < 64) seqA[tid] = seq[b0 + tid];
  } else {
    const int cidx = blk - 128;
    b0 = (cidx & 7) * 64;          // batch group (same XCD residue as A of g)
    f0 = (cidx >> 3) * 64;         // FF col group (16)
    { // W1 slab, coalesced over f
      const int fj = tid & 63, kq = tid >> 6;
      for (int kk = 0; kk < 128; ++kk) {
        const int k = kq + kk * 4;
        L.b.w1[fj * 520 + k] = (bf16_t)W1[(size_t)k * FFD + f0 + fj];
      }
    }
    if (tid < 64) b1s[tid] = b1[f0 + tid];
    hasC = (cidx < 32);
    if (hasC) {
      b0c = (cidx & 7) * 64;       // batch group (same XCD residue)
      o0 = (cidx >> 3) * 16;       // out col group (4)
      const int oj = tid & 15, kq = tid >> 4;
      for (int kk = 0; kk < 64; ++kk) {
        const int k = kq * 64 + kk;
        L.b.w2[oj * 1032 + k] = (bf16_t)W2[k * OUTD + o0 + oj];
      }
      if (tid < 16) b2s[tid] = b2[o0 + tid];
      if (tid < 64) seqC[tid] = seq[b0c + tid];
    }
  }

  // ---- pipelined time loop: iter i does A(t=i), B(t=i-1), C(t=i-2) ----
  // Barrier: monotonic counter, NO fences. Exchanged data (h/ff/hid) moves
  // via agent-scope relaxed atomics (sc1 -> L3 coherence point); each wave's
  // stores are drained (vmcnt 0) by __syncthreads before tid0 signals.
  unsigned tgt = NBLK;
  for (int it = 0; it < TT + 2; ++it, tgt += NBLK) {
    __syncthreads();
    if (tid == 0) {
      atomicAdd(bar, 1u);
      while (__hip_atomic_load(bar, __ATOMIC_RELAXED, __HIP_MEMORY_SCOPE_AGENT) < tgt) {
        __builtin_amdgcn_s_sleep(1);
      }
    }
    __syncthreads();

    if (isA) {
      if (it < TT) {
        const int t = it;
        bf16_t* hr = hb + (size_t)((t + 1) & 1) * BB * HDIM;   // non-const: atomic src
        bf16_t* hw = hb + (size_t)(t & 1) * BB * HDIM;
        bf16_t* fw = ff + (size_t)(t & 1) * BB * HDIM;
        const int rA = b0 + wv * 16 + col16;
        const float* paxf = x + ((size_t)rA * TT + t) * FDIM;
        bf16_t* pah = hr + (size_t)rA * HDIM;
        const f32x4 zz = {0.f, 0.f, 0.f, 0.f};
        f32x4 acc[4] = {zz, zz, zz, zz};
        f32x4 accn[2] = {zz, zz};
        f32x4 acci[2] = {zz, zz};
        // x part: K 0..127 feeds rz (k<128) and ni
        #pragma unroll
        for (int ks = 0; ks < 4; ++ks) {
          const int ko = ks * 32 + q8;
          const float4 u0 = *(const float4*)(paxf + ko);
          const float4 u1 = *(const float4*)(paxf + ko + 4);
          bf16x8 av;
          av[0]=(bf16_t)u0.x; av[1]=(bf16_t)u0.y; av[2]=(bf16_t)u0.z; av[3]=(bf16_t)u0.w;
          av[4]=(bf16_t)u1.x; av[5]=(bf16_t)u1.y; av[6]=(bf16_t)u1.z; av[7]=(bf16_t)u1.w;
          #pragma unroll
          for (int j = 0; j < 4; ++j) {
            const bf16x8 bv = *(const bf16x8*)&L.a.rz[(j * 16 + col16) * 648 + ko];
            acc[j] = mfma16(av, bv, acc[j]);
          }
          #pragma unroll
          for (int j = 0; j < 2; ++j) {
            const bf16x8 bv = *(const bf16x8*)&L.a.ni[(j * 16 + col16) * 136 + ko];
            acci[j] = mfma16(av, bv, acci[j]);
          }
        }
        // h part: K 0..511 feeds rz (k>=128) and nh; coherent 8B loads
        #pragma unroll 2
        for (int ks = 0; ks < 16; ++ks) {
          const int ko = ks * 32 + q8;
          u64 hq[2];
          hq[0] = __hip_atomic_load((u64*)(pah + ko),     __ATOMIC_RELAXED, __HIP_MEMORY_SCOPE_AGENT);
          hq[1] = __hip_atomic_load((u64*)(pah + ko) + 1, __ATOMIC_RELAXED, __HIP_MEMORY_SCOPE_AGENT);
          const bf16x8 av = *(const bf16x8*)hq;
          #pragma unroll
          for (int j = 0; j < 4; ++j) {
            const bf16x8 bv = *(const bf16x8*)&L.a.rz[(j * 16 + col16) * 648 + 128 + ko];
            acc[j] = mfma16(av, bv, acc[j]);
          }
          #pragma unroll
          for (int j = 0; j < 2; ++j) {
            const bf16x8 bv = *(const bf16x8*)&L.a.nh[(j * 16 + col16) * 520 + ko];
            accn[j] = mfma16(av, bv, accn[j]);
          }
        }
        // dump gate sums to LDS exchange (C/D: col=lane&15, row=q*4+reg)
        #pragma unroll
        for (int j = 0; j < 4; ++j) {
          const int sl = j >> 1, cb = (j & 1) * 16 + col16;
          #pragma unroll
          for (int rg = 0; rg < 4; ++rg)
            L.a.ex[sl][wv * 16 + q * 4 + rg][cb] = acc[j][rg];
        }
        #pragma unroll
        for (int j = 0; j < 2; ++j) {
          const int cb = j * 16 + col16;
          #pragma unroll
          for (int rg = 0; rg < 4; ++rg) {
            L.a.ex[2][wv * 16 + q * 4 + rg][cb] = accn[j][rg];
            L.a.ex[3][wv * 16 + q * 4 + rg][cb] = acci[j][rg];
          }
        }
        __syncthreads();
        // elementwise GRU update, 4 cols/thread, 8B coherent I/O
        for (int e = tid; e < 512; e += NTHR) {
          const int row = e >> 3, cq = (e & 7) << 2;
          const int bidx = b0 + row;
          u64 hp8 = __hip_atomic_load((u64*)(hr + (size_t)bidx * HDIM + c0 + cq),
                                      __ATOMIC_RELAXED, __HIP_MEMORY_SCOPE_AGENT);
          const bf16_t* hp4 = (const bf16_t*)&hp8;
          bf16_t hw4[4], fw4[4];
          const bool v = (t < seqA[row]);
          #pragma unroll
          for (int j = 0; j < 4; ++j) {
            const int c = cq + j;
            const float gr  = L.a.ex[0][row][c] + biasA[0][c];
            const float gz  = L.a.ex[1][row][c] + biasA[1][c];
            const float gnh = L.a.ex[2][row][c] + biasA[3][c];
            const float gni = L.a.ex[3][row][c] + biasA[2][c];
            const float r = sigm(gr), zg = sigm(gz);
            const float n = tanh_f(gni + r * gnh);
            const float hp = (float)hp4[j];
            const float hnew = (1.f - zg) * n + zg * hp;
            hw4[j] = (bf16_t)(v ? hnew : hp);
            fw4[j] = (bf16_t)(v ? hnew : 0.f);
          }
          __hip_atomic_store((u64*)(hw + (size_t)bidx * HDIM + c0 + cq), *(u64*)hw4,
                             __ATOMIC_RELAXED, __HIP_MEMORY_SCOPE_AGENT);
          __hip_atomic_store((u64*)(fw + (size_t)bidx * HDIM + c0 + cq), *(u64*)fw4,
                             __ATOMIC_RELAXED, __HIP_MEMORY_SCOPE_AGENT);
        }
      }
    } else {
      if (it >= 1 && it <= TT) {           // FF1 for t = it-1
        const int t = it - 1;
        bf16_t* fr = ff + (size_t)(t & 1) * BB * HDIM;
        bf16_t* hwid = hd + (size_t)(t & 1) * BB * FFD;
        const int rB = b0 + wv * 16 + col16;
        bf16_t* pa = fr + (size_t)rB * HDIM;
        const f32x4 zz = {0.f, 0.f, 0.f, 0.f};
        f32x4 acc[4] = {zz, zz, zz, zz};
        #pragma unroll 4
        for (int ks = 0; ks < 16; ++ks) {
          const int ko = ks * 32 + q8;
          u64 fq[2];
          fq[0] = __hip_atomic_load((u64*)(pa + ko),     __ATOMIC_RELAXED, __HIP_MEMORY_SCOPE_AGENT);
          fq[1] = __hip_atomic_load((u64*)(pa + ko) + 1, __ATOMIC_RELAXED, __HIP_MEMORY_SCOPE_AGENT);
          const bf16x8 av = *(const bf16x8*)fq;
          #pragma unroll
          for (int j = 0; j < 4; ++j) {
            const bf16x8 bv = *(const bf16x8*)&L.b.w1[(j * 16 + col16) * 520 + ko];
            acc[j] = mfma16(av, bv, acc[j]);
          }
        }
        // relu + bias -> LDS restage -> contiguous 8B coherent stores
        #pragma unroll
        for (int j = 0; j < 4; ++j) {
          const int fc = j * 16 + col16;
          #pragma unroll
          for (int rg = 0; rg < 4; ++rg)
            L.b.st[(wv * 16 + q * 4 + rg) * 72 + fc] =
                (bf16_t)fmaxf(acc[j][rg] + b1s[fc], 0.f);
        }
        __syncthreads();
        for (int w = tid; w < 1024; w += NTHR) {
          const int r = w >> 4, cq = (w & 15) * 4;
          const u64 pk = *(const u64*)&L.b.st[r * 72 + cq];
          __hip_atomic_store((u64*)(hwid + (size_t)(b0 + r) * FFD + f0 + cq), pk,
                             __ATOMIC_RELAXED, __HIP_MEMORY_SCOPE_AGENT);
        }
      }
      if (hasC && it >= 2) {               // FF2 for t = it-2
        const int t = it - 2;
        bf16_t* hr2 = hd + (size_t)(t & 1) * BB * FFD;
        const int rC = b0c + wv * 16 + col16;
        bf16_t* pa = hr2 + (size_t)rC * FFD;
        f32x4 acc = {0.f, 0.f, 0.f, 0.f};
        #pragma unroll 4
        for (int ks = 0; ks < 32; ++ks) {
          const int ko = ks * 32 + q8;
          u64 hq[2];
          hq[0] = __hip_atomic_load((u64*)(pa + ko),     __ATOMIC_RELAXED, __HIP_MEMORY_SCOPE_AGENT);
          hq[1] = __hip_atomic_load((u64*)(pa + ko) + 1, __ATOMIC_RELAXED, __HIP_MEMORY_SCOPE_AGENT);
          const bf16x8 av = *(const bf16x8*)hq;
          const bf16x8 bv = *(const bf16x8*)&L.b.w2[col16 * 1032 + ko];
          acc = mfma16(av, bv, acc);
        }
        #pragma unroll
        for (int rg = 0; rg < 4; ++rg) {
          const int lr = wv * 16 + q * 4 + rg;
          const int rb = b0c + lr;
          const float v = acc[rg] + b2s[col16];
          out[((size_t)rb * TT + t) * OUTD + o0 + col16] = (t < seqC[lr]) ? v : PADV;
        }
      }
    }
  }
}

extern "C" void kernel_launch(void* const* d_in, const int* in_sizes, int n_in,
                              void* d_out, int out_size, void* d_ws, size_t ws_size,
                              hipStream_t stream) {
  const float* x   = (const float*)d_in[0];
  const int*   seq = (const int*)d_in[1];
  const float* Wih = (const float*)d_in[2];
  const float* Whh = (const float*)d_in[3];
  const float* bih = (const float*)d_in[4];
  const float* bhh = (const float*)d_in[5];
  const float* W1  = (const float*)d_in[6];
  const float* b1  = (const float*)d_in[7];
  const float* W2  = (const float*)d_in[8];
  const float* b2  = (const float*)d_in[9];
  float* out = (float*)d_out;
  char* ws = (char*)d_ws;

  unsigned* bar = (unsigned*)ws;                       // barrier counter
  bf16_t* hb = (bf16_t*)(ws + 256);                    // h ping-pong  2*B*H
  bf16_t* ff = hb + (size_t)2 * BB * HDIM;             // ffin ping-pong
  bf16_t* hd = ff + (size_t)2 * BB * HDIM;             // hid ping-pong 2*B*FF
  // total scratch ~4.2 MB

  hipMemsetAsync(ws, 0, 256, stream);
  void* args[] = {&x, &seq, &Wih, &Whh, &bih, &bhh, &W1, &b1, &W2, &b2,
                  &out, &hb, &ff, &hd, &bar};
  hipLaunchCooperativeKernel((void*)gru_net_kernel, dim3(NBLK), dim3(NTHR),
                             args, 0, stream);
}

// Round 10
// 3872.659 us; speedup vs baseline: 2.1447x; 1.2560x over previous
//
#include <hip/hip_runtime.h>

#define BB 512
#define TT 256
#define FDIM 128
#define HDIM 512
#define FFD 1024
#define OUTD 64
#define PADV -999.0f
#define NBLK 256
#define NTHR 256

typedef __bf16 bf16_t;
typedef bf16_t bf16x8 __attribute__((ext_vector_type(8)));
typedef float f32x4 __attribute__((ext_vector_type(4)));
typedef unsigned long long u64;

// LDS: role-specialized weight slabs (resident across all 256 time steps).
union LdsU {
  struct {                      // A-role (GRU gates), 128 blocks
    bf16_t rz[64 * 648];        // [r|z] slab, K=640 concat [x|h], col-major
    bf16_t nh[32 * 520];        // h_n slab, K=512 (h only)
    bf16_t ni[32 * 136];        // i_n slab, K=128 (x only)
    float  ex[4][64][33];       // gate exchange: [r,z,nh,ni][row][col] (+1 pad)
  } a;
  struct {                      // B-role (FF1) + C-addon (FF2), 128 blocks
    bf16_t w1[64 * 520];        // W1 slab, K=512
    bf16_t w2[16 * 1032];       // W2 slab, K=1024
    bf16_t st[64 * 72];         // FF1 output restage for contiguous 8B stores
  } b;
};

__device__ __forceinline__ f32x4 mfma16(bf16x8 a, bf16x8 b, f32x4 c) {
  return __builtin_amdgcn_mfma_f32_16x16x32_bf16(a, b, c, 0, 0, 0);
}
__device__ __forceinline__ float sigm(float x) { return 1.f / (1.f + __expf(-x)); }
__device__ __forceinline__ float tanh_f(float x) { return 2.f / (1.f + __expf(-2.f * x)) - 1.f; }

// LESSONS (stub-failure = silent compile fail -> harness fallback):
//  1. __hip_atomic_* pointer args must be NON-CONST.
//  2. NO prefetch arrays >= 64 VGPRs (e.g. u64[32]) feeding unrolled MFMA
//     loops — register allocator blows up. Keep hq[2]-style only.

__global__ __launch_bounds__(NTHR) void gru_net_kernel(
    const float* __restrict__ x, const int* __restrict__ seq,
    const float* __restrict__ Wih, const float* __restrict__ Whh,
    const float* __restrict__ bih, const float* __restrict__ bhh,
    const float* __restrict__ W1, const float* __restrict__ b1,
    const float* __restrict__ W2, const float* __restrict__ b2,
    float* __restrict__ out,
    bf16_t* __restrict__ hb, bf16_t* __restrict__ ff, bf16_t* __restrict__ hd,
    unsigned* __restrict__ bar) {
  __shared__ LdsU L;
  __shared__ float biasA[4][32];   // [b_r, b_z, b_in, b_hn] for block's 32 h-cols
  __shared__ float b1s[64];
  __shared__ float b2s[16];
  __shared__ int   seqA[64];
  __shared__ int   seqC[64];

  const int blk = blockIdx.x, tid = threadIdx.x;
  const int wv = tid >> 6, lane = tid & 63;
  const int q = lane >> 4, col16 = lane & 15, q8 = q * 8;
  const bool isA = blk < 128;

  // ---- preamble: zero h_{-1} buffer (hb[1]) via L3-coherent stores ----
  {
    u64* hz = (u64*)(hb + (size_t)BB * HDIM);
    const int nz = BB * HDIM / 4;
    for (int idx = blk * NTHR + tid; idx < nz; idx += NBLK * NTHR)
      __hip_atomic_store(hz + idx, 0ull, __ATOMIC_RELAXED, __HIP_MEMORY_SCOPE_AGENT);
  }

  // XCD-locality remap: batch-group = blk%8 so (with round-robin blk->XCD
  // dispatch) each group's A producers and B/C consumers share one XCD L2.
  int b0 = 0, c0 = 0, f0 = 0, b0c = 0, o0 = 0;
  bool hasC = false;
  if (isA) {
    b0 = (blk & 7) * 64;           // batch row group (8)
    c0 = (blk >> 3) * 32;          // h-col group (16)
    { // rz slab: cols 0..31 = r (Wih/Whh rows c0+cj), 32..63 = z (rows 512+...)
      const int cj = tid & 63, kq = tid >> 6;
      const int g = (cj < 32) ? (c0 + cj) : (512 + c0 + (cj - 32));
      for (int kk = 0; kk < 160; ++kk) {
        const int k = kq * 160 + kk;
        const float w = (k < 128) ? Wih[g * FDIM + k]
                                  : Whh[(size_t)g * HDIM + (k - 128)];
        L.a.rz[cj * 648 + k] = (bf16_t)w;
      }
    }
    { // nh (K=512) and ni (K=128) slabs: n-gate rows 1024+c0+cj
      const int cj = tid & 31, kq = tid >> 5;
      const int g = 1024 + c0 + cj;
      for (int kk = 0; kk < 64; ++kk) {
        const int k = kq * 64 + kk;
        L.a.nh[cj * 520 + k] = (bf16_t)Whh[(size_t)g * HDIM + k];
      }
      for (int kk = 0; kk < 16; ++kk) {
        const int k = kq * 16 + kk;
        L.a.ni[cj * 136 + k] = (bf16_t)Wih[g * FDIM + k];
      }
    }
    if (tid < 32) {
      biasA[0][tid] = bih[c0 + tid] + bhh[c0 + tid];
      biasA[1][tid] = bih[512 + c0 + tid] + bhh[512 + c0 + tid];
      biasA[2][tid] = bih[1024 + c0 + tid];   // i_n bias
      biasA[3][tid] = bhh[1024 + c0 + tid];   // h_n bias
    }
    if (tid < 64) seqA[tid] = seq[b0 + tid];
  } else {
    const int cidx = blk - 128;
    b0 = (cidx & 7) * 64;          // batch group (same XCD residue as A of g)
    f0 = (cidx >> 3) * 64;         // FF col group (16)
    { // W1 slab, coalesced over f
      const int fj = tid & 63, kq = tid >> 6;
      for (int kk = 0; kk < 128; ++kk) {
        const int k = kq + kk * 4;
        L.b.w1[fj * 520 + k] = (bf16_t)W1[(size_t)k * FFD + f0 + fj];
      }
    }
    if (tid < 64) b1s[tid] = b1[f0 + tid];
    hasC = (cidx < 32);
    if (hasC) {
      b0c = (cidx & 7) * 64;       // batch group (same XCD residue)
      o0 = (cidx >> 3) * 16;       // out col group (4)
      const int oj = tid & 15, kq = tid >> 4;
      for (int kk = 0; kk < 64; ++kk) {
        const int k = kq * 64 + kk;
        L.b.w2[oj * 1032 + k] = (bf16_t)W2[k * OUTD + o0 + oj];
      }
      if (tid < 16) b2s[tid] = b2[o0 + tid];
      if (tid < 64) seqC[tid] = seq[b0c + tid];
    }
  }

  // ---- pipelined time loop: iter i does A(t=i), B(t=i-1), C(t=i-2) ----
  // Barrier: 8 sharded monotonic counters (128B apart -> 8-way parallel RMW
  // arrival instead of one serialized line), NO fences. Data plane is sc1
  // (L3 coherence point); each wave's stores drain (vmcnt 0) at
  // __syncthreads before tid0 signals.
  unsigned tgt = NBLK;
  for (int it = 0; it < TT + 2; ++it, tgt += NBLK) {
    __syncthreads();
    if (tid == 0) {
      atomicAdd(bar + (blk & 7) * 32, 1u);
      for (;;) {
        const unsigned s0 = __hip_atomic_load(bar,          __ATOMIC_RELAXED, __HIP_MEMORY_SCOPE_AGENT);
        const unsigned s1 = __hip_atomic_load(bar + 1 * 32, __ATOMIC_RELAXED, __HIP_MEMORY_SCOPE_AGENT);
        const unsigned s2 = __hip_atomic_load(bar + 2 * 32, __ATOMIC_RELAXED, __HIP_MEMORY_SCOPE_AGENT);
        const unsigned s3 = __hip_atomic_load(bar + 3 * 32, __ATOMIC_RELAXED, __HIP_MEMORY_SCOPE_AGENT);
        const unsigned s4 = __hip_atomic_load(bar + 4 * 32, __ATOMIC_RELAXED, __HIP_MEMORY_SCOPE_AGENT);
        const unsigned s5 = __hip_atomic_load(bar + 5 * 32, __ATOMIC_RELAXED, __HIP_MEMORY_SCOPE_AGENT);
        const unsigned s6 = __hip_atomic_load(bar + 6 * 32, __ATOMIC_RELAXED, __HIP_MEMORY_SCOPE_AGENT);
        const unsigned s7 = __hip_atomic_load(bar + 7 * 32, __ATOMIC_RELAXED, __HIP_MEMORY_SCOPE_AGENT);
        if (s0 + s1 + s2 + s3 + s4 + s5 + s6 + s7 >= tgt) break;
        __builtin_amdgcn_s_sleep(1);
      }
    }
    __syncthreads();

    if (isA) {
      if (it < TT) {
        const int t = it;
        bf16_t* hr = hb + (size_t)((t + 1) & 1) * BB * HDIM;
        bf16_t* hw = hb + (size_t)(t & 1) * BB * HDIM;
        bf16_t* fw = ff + (size_t)(t & 1) * BB * HDIM;
        const int rA = b0 + wv * 16 + col16;
        const float* paxf = x + ((size_t)rA * TT + t) * FDIM;
        bf16_t* pah = hr + (size_t)rA * HDIM;
        const f32x4 zz = {0.f, 0.f, 0.f, 0.f};
        f32x4 acc[4] = {zz, zz, zz, zz};
        f32x4 accn[2] = {zz, zz};
        f32x4 acci[2] = {zz, zz};
        // x part: K 0..127 feeds rz (k<128) and ni
        #pragma unroll
        for (int ks = 0; ks < 4; ++ks) {
          const int ko = ks * 32 + q8;
          const float4 u0 = *(const float4*)(paxf + ko);
          const float4 u1 = *(const float4*)(paxf + ko + 4);
          bf16x8 av;
          av[0]=(bf16_t)u0.x; av[1]=(bf16_t)u0.y; av[2]=(bf16_t)u0.z; av[3]=(bf16_t)u0.w;
          av[4]=(bf16_t)u1.x; av[5]=(bf16_t)u1.y; av[6]=(bf16_t)u1.z; av[7]=(bf16_t)u1.w;
          #pragma unroll
          for (int j = 0; j < 4; ++j) {
            const bf16x8 bv = *(const bf16x8*)&L.a.rz[(j * 16 + col16) * 648 + ko];
            acc[j] = mfma16(av, bv, acc[j]);
          }
          #pragma unroll
          for (int j = 0; j < 2; ++j) {
            const bf16x8 bv = *(const bf16x8*)&L.a.ni[(j * 16 + col16) * 136 + ko];
            acci[j] = mfma16(av, bv, acci[j]);
          }
        }
        // h part: K 0..511 feeds rz (k>=128) and nh; coherent 8B loads
        #pragma unroll 2
        for (int ks = 0; ks < 16; ++ks) {
          const int ko = ks * 32 + q8;
          u64 hq[2];
          hq[0] = __hip_atomic_load((u64*)(pah + ko),     __ATOMIC_RELAXED, __HIP_MEMORY_SCOPE_AGENT);
          hq[1] = __hip_atomic_load((u64*)(pah + ko) + 1, __ATOMIC_RELAXED, __HIP_MEMORY_SCOPE_AGENT);
          const bf16x8 av = *(const bf16x8*)hq;
          #pragma unroll
          for (int j = 0; j < 4; ++j) {
            const bf16x8 bv = *(const bf16x8*)&L.a.rz[(j * 16 + col16) * 648 + 128 + ko];
            acc[j] = mfma16(av, bv, acc[j]);
          }
          #pragma unroll
          for (int j = 0; j < 2; ++j) {
            const bf16x8 bv = *(const bf16x8*)&L.a.nh[(j * 16 + col16) * 520 + ko];
            accn[j] = mfma16(av, bv, accn[j]);
          }
        }
        // dump gate sums to LDS exchange (C/D: col=lane&15, row=q*4+reg)
        #pragma unroll
        for (int j = 0; j < 4; ++j) {
          const int sl = j >> 1, cb = (j & 1) * 16 + col16;
          #pragma unroll
          for (int rg = 0; rg < 4; ++rg)
            L.a.ex[sl][wv * 16 + q * 4 + rg][cb] = acc[j][rg];
        }
        #pragma unroll
        for (int j = 0; j < 2; ++j) {
          const int cb = j * 16 + col16;
          #pragma unroll
          for (int rg = 0; rg < 4; ++rg) {
            L.a.ex[2][wv * 16 + q * 4 + rg][cb] = accn[j][rg];
            L.a.ex[3][wv * 16 + q * 4 + rg][cb] = acci[j][rg];
          }
        }
        __syncthreads();
        // elementwise GRU update, 4 cols/thread, 8B coherent I/O
        for (int e = tid; e < 512; e += NTHR) {
          const int row = e >> 3, cq = (e & 7) << 2;
          const int bidx = b0 + row;
          u64 hp8 = __hip_atomic_load((u64*)(hr + (size_t)bidx * HDIM + c0 + cq),
                                      __ATOMIC_RELAXED, __HIP_MEMORY_SCOPE_AGENT);
          const bf16_t* hp4 = (const bf16_t*)&hp8;
          bf16_t hw4[4], fw4[4];
          const bool v = (t < seqA[row]);
          #pragma unroll
          for (int j = 0; j < 4; ++j) {
            const int c = cq + j;
            const float gr  = L.a.ex[0][row][c] + biasA[0][c];
            const float gz  = L.a.ex[1][row][c] + biasA[1][c];
            const float gnh = L.a.ex[2][row][c] + biasA[3][c];
            const float gni = L.a.ex[3][row][c] + biasA[2][c];
            const float r = sigm(gr), zg = sigm(gz);
            const float n = tanh_f(gni + r * gnh);
            const float hp = (float)hp4[j];
            const float hnew = (1.f - zg) * n + zg * hp;
            hw4[j] = (bf16_t)(v ? hnew : hp);
            fw4[j] = (bf16_t)(v ? hnew : 0.f);
          }
          __hip_atomic_store((u64*)(hw + (size_t)bidx * HDIM + c0 + cq), *(u64*)hw4,
                             __ATOMIC_RELAXED, __HIP_MEMORY_SCOPE_AGENT);
          __hip_atomic_store((u64*)(fw + (size_t)bidx * HDIM + c0 + cq), *(u64*)fw4,
                             __ATOMIC_RELAXED, __HIP_MEMORY_SCOPE_AGENT);
        }
      }
    } else {
      if (it >= 1 && it <= TT) {           // FF1 for t = it-1
        const int t = it - 1;
        bf16_t* fr = ff + (size_t)(t & 1) * BB * HDIM;
        bf16_t* hwid = hd + (size_t)(t & 1) * BB * FFD;
        const int rB = b0 + wv * 16 + col16;
        bf16_t* pa = fr + (size_t)rB * HDIM;
        const f32x4 zz = {0.f, 0.f, 0.f, 0.f};
        f32x4 acc[4] = {zz, zz, zz, zz};
        #pragma unroll 4
        for (int ks = 0; ks < 16; ++ks) {
          const int ko = ks * 32 + q8;
          u64 fq[2];
          fq[0] = __hip_atomic_load((u64*)(pa + ko),     __ATOMIC_RELAXED, __HIP_MEMORY_SCOPE_AGENT);
          fq[1] = __hip_atomic_load((u64*)(pa + ko) + 1, __ATOMIC_RELAXED, __HIP_MEMORY_SCOPE_AGENT);
          const bf16x8 av = *(const bf16x8*)fq;
          #pragma unroll
          for (int j = 0; j < 4; ++j) {
            const bf16x8 bv = *(const bf16x8*)&L.b.w1[(j * 16 + col16) * 520 + ko];
            acc[j] = mfma16(av, bv, acc[j]);
          }
        }
        // relu + bias -> LDS restage -> contiguous 8B coherent stores
        #pragma unroll
        for (int j = 0; j < 4; ++j) {
          const int fc = j * 16 + col16;
          #pragma unroll
          for (int rg = 0; rg < 4; ++rg)
            L.b.st[(wv * 16 + q * 4 + rg) * 72 + fc] =
                (bf16_t)fmaxf(acc[j][rg] + b1s[fc], 0.f);
        }
        __syncthreads();
        for (int w = tid; w < 1024; w += NTHR) {
          const int r = w >> 4, cq = (w & 15) * 4;
          const u64 pk = *(const u64*)&L.b.st[r * 72 + cq];
          __hip_atomic_store((u64*)(hwid + (size_t)(b0 + r) * FFD + f0 + cq), pk,
                             __ATOMIC_RELAXED, __HIP_MEMORY_SCOPE_AGENT);
        }
      }
      if (hasC && it >= 2) {               // FF2 for t = it-2
        const int t = it - 2;
        bf16_t* hr2 = hd + (size_t)(t & 1) * BB * FFD;
        const int rC = b0c + wv * 16 + col16;
        bf16_t* pa = hr2 + (size_t)rC * FFD;
        f32x4 acc = {0.f, 0.f, 0.f, 0.f};
        #pragma unroll 4
        for (int ks = 0; ks < 32; ++ks) {
          const int ko = ks * 32 + q8;
          u64 hq[2];
          hq[0] = __hip_atomic_load((u64*)(pa + ko),     __ATOMIC_RELAXED, __HIP_MEMORY_SCOPE_AGENT);
          hq[1] = __hip_atomic_load((u64*)(pa + ko) + 1, __ATOMIC_RELAXED, __HIP_MEMORY_SCOPE_AGENT);
          const bf16x8 av = *(const bf16x8*)hq;
          const bf16x8 bv = *(const bf16x8*)&L.b.w2[col16 * 1032 + ko];
          acc = mfma16(av, bv, acc);
        }
        #pragma unroll
        for (int rg = 0; rg < 4; ++rg) {
          const int lr = wv * 16 + q * 4 + rg;
          const int rb = b0c + lr;
          const float v = acc[rg] + b2s[col16];
          out[((size_t)rb * TT + t) * OUTD + o0 + col16] = (t < seqC[lr]) ? v : PADV;
        }
      }
    }
  }
}

extern "C" void kernel_launch(void* const* d_in, const int* in_sizes, int n_in,
                              void* d_out, int out_size, void* d_ws, size_t ws_size,
                              hipStream_t stream) {
  const float* x   = (const float*)d_in[0];
  const int*   seq = (const int*)d_in[1];
  const float* Wih = (const float*)d_in[2];
  const float* Whh = (const float*)d_in[3];
  const float* bih = (const float*)d_in[4];
  const float* bhh = (const float*)d_in[5];
  const float* W1  = (const float*)d_in[6];
  const float* b1  = (const float*)d_in[7];
  const float* W2  = (const float*)d_in[8];
  const float* b2  = (const float*)d_in[9];
  float* out = (float*)d_out;
  char* ws = (char*)d_ws;

  unsigned* bar = (unsigned*)ws;                       // 8 counters, 128B apart
  bf16_t* hb = (bf16_t*)(ws + 1024);                   // h ping-pong  2*B*H
  bf16_t* ff = hb + (size_t)2 * BB * HDIM;             // ffin ping-pong
  bf16_t* hd = ff + (size_t)2 * BB * HDIM;             // hid ping-pong 2*B*FF
  // total scratch ~4.2 MB (same envelope as R5/R7)

  hipMemsetAsync(ws, 0, 1024, stream);
  void* args[] = {&x, &seq, &Wih, &Whh, &bih, &bhh, &W1, &b1, &W2, &b2,
                  &out, &hb, &ff, &hd, &bar};
  hipLaunchCooperativeKernel((void*)gru_net_kernel, dim3(NBLK), dim3(NTHR),
                             args, 0, stream);
}

// Round 11
// 3866.444 us; speedup vs baseline: 2.1482x; 1.0016x over previous
//
#include <hip/hip_runtime.h>

#define BB 512
#define TT 256
#define FDIM 128
#define HDIM 512
#define FFD 1024
#define OUTD 64
#define PADV -999.0f
#define NBLK 256
#define NTHR 256

typedef __bf16 bf16_t;
typedef bf16_t bf16x8 __attribute__((ext_vector_type(8)));
typedef float f32x4 __attribute__((ext_vector_type(4)));
typedef unsigned long long u64;

// Fragment-major LDS slabs: each MFMA B-fragment (16 cols x 32 K) stored as
// 64 lanes x 16B contiguous -> ds_read_b128 at lane*16 (linear, conflict-
// free ~12cy). R10's col-pitch layout put all 64 lanes in 8 of 32 banks
// (8-way conflict, SQ_LDS_BANK_CONFLICT 6.15e8).
union LdsU {
  struct {                        // A-role (GRU gates), 128 blocks
    bf16_t rzf[80 * 64 * 8];      // [j<4][ks<20: 0..3 x-part, 4..19 h-part]
    bf16_t nhf[32 * 64 * 8];      // [j2<2][ks<16] h_n (Whh rows 1024+)
    bf16_t nif[8 * 64 * 8];       // [j2<2][ks<4]  i_n (Wih rows 1024+)
    float  ex[4][64][33];         // gate exchange [r,z,nh,ni][row][col]
  } a;
  struct {                        // B-role (FF1) + C-addon (FF2), 128 blocks
    bf16_t w1f[64 * 64 * 8];      // [j<4][ks<16]
    bf16_t w2f[32 * 64 * 8];      // [ks<32]
    bf16_t st[64 * 72];           // FF1 output restage
  } b;
};

__device__ __forceinline__ f32x4 mfma16(bf16x8 a, bf16x8 b, f32x4 c) {
  return __builtin_amdgcn_mfma_f32_16x16x32_bf16(a, b, c, 0, 0, 0);
}
__device__ __forceinline__ float sigm(float x) { return 1.f / (1.f + __expf(-x)); }
__device__ __forceinline__ float tanh_f(float x) { return 2.f / (1.f + __expf(-2.f * x)) - 1.f; }

// LESSONS (stub-failure = silent compile fail -> harness fallback):
//  1. __hip_atomic_* pointer args must be NON-CONST, used inline.
//  2. NO prefetch arrays >= 64 VGPRs feeding unrolled MFMA loops.

__global__ __launch_bounds__(NTHR) void gru_net_kernel(
    const float* __restrict__ x, const int* __restrict__ seq,
    const float* __restrict__ Wih, const float* __restrict__ Whh,
    const float* __restrict__ bih, const float* __restrict__ bhh,
    const float* __restrict__ W1, const float* __restrict__ b1,
    const float* __restrict__ W2, const float* __restrict__ b2,
    float* __restrict__ out,
    bf16_t* __restrict__ hb, bf16_t* __restrict__ ff, bf16_t* __restrict__ hd,
    unsigned* __restrict__ bar) {
  __shared__ LdsU L;
  __shared__ float biasA[4][32];
  __shared__ float b1s[64];
  __shared__ float b2s[16];
  __shared__ int   seqA[64];
  __shared__ int   seqC[64];

  const int blk = blockIdx.x, tid = threadIdx.x;
  const int wv = tid >> 6, lane = tid & 63;
  const int q = lane >> 4, col16 = lane & 15, q8 = q * 8;
  const bool isA = blk < 128;

  // ---- preamble: zero h_{-1} buffer (hb[1]) via L3-coherent stores ----
  {
    u64* hz = (u64*)(hb + (size_t)BB * HDIM);
    const int nz = BB * HDIM / 4;
    for (int idx = blk * NTHR + tid; idx < nz; idx += NBLK * NTHR)
      __hip_atomic_store(hz + idx, 0ull, __ATOMIC_RELAXED, __HIP_MEMORY_SCOPE_AGENT);
  }

  // XCD-locality remap: batch-group = blk%8 (round-robin blk->XCD) so each
  // group's A producers and B/C consumers share one XCD L2.
  int b0 = 0, c0 = 0, f0 = 0, b0c = 0, o0 = 0;
  bool hasC = false;
  if (isA) {
    b0 = (blk & 7) * 64;           // batch row group (8)
    c0 = (blk >> 3) * 32;          // h-col group (16)
    // rzf: frag fi=j*20+ks; lane(q,c) elem e = W[grow(j*16+c)][k], where
    // ks<4 -> Wih k=ks*32+q*8+e ; ks>=4 -> Whh k=(ks-4)*32+q*8+e
    for (int i = tid; i < 80 * 64; i += NTHR) {
      const int ln = i & 63, fi = i >> 6;
      const int j = fi / 20, ks = fi - j * 20;
      const int cc = ln & 15, qq = ln >> 4;
      const int colj = j * 16 + cc;
      const int grow = (colj < 32) ? (c0 + colj) : (512 + c0 + (colj - 32));
      bf16_t* dst = &L.a.rzf[(size_t)i * 8];
      if (ks < 4) {
        const float* src = Wih + (size_t)grow * FDIM + ks * 32 + qq * 8;
        for (int e = 0; e < 8; ++e) dst[e] = (bf16_t)src[e];
      } else {
        const float* src = Whh + (size_t)grow * HDIM + (ks - 4) * 32 + qq * 8;
        for (int e = 0; e < 8; ++e) dst[e] = (bf16_t)src[e];
      }
    }
    for (int i = tid; i < 32 * 64; i += NTHR) {   // nhf: fi=j2*16+ks
      const int ln = i & 63, fi = i >> 6;
      const int j2 = fi >> 4, ks = fi & 15;
      const int cc = ln & 15, qq = ln >> 4;
      const int grow = 1024 + c0 + j2 * 16 + cc;
      const float* src = Whh + (size_t)grow * HDIM + ks * 32 + qq * 8;
      bf16_t* dst = &L.a.nhf[(size_t)i * 8];
      for (int e = 0; e < 8; ++e) dst[e] = (bf16_t)src[e];
    }
    for (int i = tid; i < 8 * 64; i += NTHR) {    // nif: fi=j2*4+ks
      const int ln = i & 63, fi = i >> 6;
      const int j2 = fi >> 2, ks = fi & 3;
      const int cc = ln & 15, qq = ln >> 4;
      const int grow = 1024 + c0 + j2 * 16 + cc;
      const float* src = Wih + (size_t)grow * FDIM + ks * 32 + qq * 8;
      bf16_t* dst = &L.a.nif[(size_t)i * 8];
      for (int e = 0; e < 8; ++e) dst[e] = (bf16_t)src[e];
    }
    if (tid < 32) {
      biasA[0][tid] = bih[c0 + tid] + bhh[c0 + tid];
      biasA[1][tid] = bih[512 + c0 + tid] + bhh[512 + c0 + tid];
      biasA[2][tid] = bih[1024 + c0 + tid];   // i_n bias
      biasA[3][tid] = bhh[1024 + c0 + tid];   // h_n bias
    }
    if (tid < 64) seqA[tid] = seq[b0 + tid];
  } else {
    const int cidx = blk - 128;
    b0 = (cidx & 7) * 64;          // batch group (same XCD residue as A)
    f0 = (cidx >> 3) * 64;         // FF col group (16)
    for (int i = tid; i < 64 * 64; i += NTHR) {   // w1f: fi=j*16+ks
      const int ln = i & 63, fi = i >> 6;
      const int j = fi >> 4, ks = fi & 15;
      const int cc = ln & 15, qq = ln >> 4;
      const int fcol = f0 + j * 16 + cc;
      const int kb = ks * 32 + qq * 8;
      bf16_t* dst = &L.b.w1f[(size_t)i * 8];
      for (int e = 0; e < 8; ++e) dst[e] = (bf16_t)W1[(size_t)(kb + e) * FFD + fcol];
    }
    if (tid < 64) b1s[tid] = b1[f0 + tid];
    hasC = (cidx < 32);
    if (hasC) {
      b0c = (cidx & 7) * 64;       // batch group (same XCD residue)
      o0 = (cidx >> 3) * 16;       // out col group (4)
      for (int i = tid; i < 32 * 64; i += NTHR) { // w2f: fi=ks
        const int ln = i & 63, ks = i >> 6;
        const int cc = ln & 15, qq = ln >> 4;
        const int kb = ks * 32 + qq * 8;
        bf16_t* dst = &L.b.w2f[(size_t)i * 8];
        for (int e = 0; e < 8; ++e) dst[e] = (bf16_t)W2[(kb + e) * OUTD + o0 + cc];
      }
      if (tid < 16) b2s[tid] = b2[o0 + tid];
      if (tid < 64) seqC[tid] = seq[b0c + tid];
    }
  }

  // ---- pipelined time loop: iter i does A(t=i), B(t=i-1), C(t=i-2) ----
  // Barrier: 8 sharded monotonic counters (128B apart), NO fences. Data
  // plane is sc1 (L3 coherence point); stores drain at __syncthreads.
  unsigned tgt = NBLK;
  for (int it = 0; it < TT + 2; ++it, tgt += NBLK) {
    __syncthreads();
    if (tid == 0) {
      atomicAdd(bar + (blk & 7) * 32, 1u);
      for (;;) {
        const unsigned s0 = __hip_atomic_load(bar,          __ATOMIC_RELAXED, __HIP_MEMORY_SCOPE_AGENT);
        const unsigned s1 = __hip_atomic_load(bar + 1 * 32, __ATOMIC_RELAXED, __HIP_MEMORY_SCOPE_AGENT);
        const unsigned s2 = __hip_atomic_load(bar + 2 * 32, __ATOMIC_RELAXED, __HIP_MEMORY_SCOPE_AGENT);
        const unsigned s3 = __hip_atomic_load(bar + 3 * 32, __ATOMIC_RELAXED, __HIP_MEMORY_SCOPE_AGENT);
        const unsigned s4 = __hip_atomic_load(bar + 4 * 32, __ATOMIC_RELAXED, __HIP_MEMORY_SCOPE_AGENT);
        const unsigned s5 = __hip_atomic_load(bar + 5 * 32, __ATOMIC_RELAXED, __HIP_MEMORY_SCOPE_AGENT);
        const unsigned s6 = __hip_atomic_load(bar + 6 * 32, __ATOMIC_RELAXED, __HIP_MEMORY_SCOPE_AGENT);
        const unsigned s7 = __hip_atomic_load(bar + 7 * 32, __ATOMIC_RELAXED, __HIP_MEMORY_SCOPE_AGENT);
        if (s0 + s1 + s2 + s3 + s4 + s5 + s6 + s7 >= tgt) break;
        __builtin_amdgcn_s_sleep(1);
      }
    }
    __syncthreads();

    if (isA) {
      if (it < TT) {
        const int t = it;
        bf16_t* hr = hb + (size_t)((t + 1) & 1) * BB * HDIM;
        bf16_t* hw = hb + (size_t)(t & 1) * BB * HDIM;
        bf16_t* fw = ff + (size_t)(t & 1) * BB * HDIM;
        const int rA = b0 + wv * 16 + col16;
        const float* paxf = x + ((size_t)rA * TT + t) * FDIM;
        bf16_t* pah = hr + (size_t)rA * HDIM;
        const f32x4 zz = {0.f, 0.f, 0.f, 0.f};
        f32x4 acc[4] = {zz, zz, zz, zz};
        f32x4 accn[2] = {zz, zz};
        f32x4 acci[2] = {zz, zz};
        // x part: ks 0..3 feeds rzf (x-frags) and nif
        #pragma unroll
        for (int ks = 0; ks < 4; ++ks) {
          const int ko = ks * 32 + q8;
          const float4 u0 = *(const float4*)(paxf + ko);
          const float4 u1 = *(const float4*)(paxf + ko + 4);
          bf16x8 av;
          av[0]=(bf16_t)u0.x; av[1]=(bf16_t)u0.y; av[2]=(bf16_t)u0.z; av[3]=(bf16_t)u0.w;
          av[4]=(bf16_t)u1.x; av[5]=(bf16_t)u1.y; av[6]=(bf16_t)u1.z; av[7]=(bf16_t)u1.w;
          #pragma unroll
          for (int j = 0; j < 4; ++j) {
            const bf16x8 bv = *(const bf16x8*)&L.a.rzf[(size_t)((j * 20 + ks) * 64 + lane) * 8];
            acc[j] = mfma16(av, bv, acc[j]);
          }
          #pragma unroll
          for (int j = 0; j < 2; ++j) {
            const bf16x8 bv = *(const bf16x8*)&L.a.nif[(size_t)((j * 4 + ks) * 64 + lane) * 8];
            acci[j] = mfma16(av, bv, acci[j]);
          }
        }
        // h part: ks 0..15 feeds rzf (h-frags) and nhf; coherent 8B loads
        #pragma unroll 4
        for (int ks = 0; ks < 16; ++ks) {
          const int ko = ks * 32 + q8;
          u64 hq[2];
          hq[0] = __hip_atomic_load((u64*)(pah + ko),     __ATOMIC_RELAXED, __HIP_MEMORY_SCOPE_AGENT);
          hq[1] = __hip_atomic_load((u64*)(pah + ko) + 1, __ATOMIC_RELAXED, __HIP_MEMORY_SCOPE_AGENT);
          const bf16x8 av = *(const bf16x8*)hq;
          #pragma unroll
          for (int j = 0; j < 4; ++j) {
            const bf16x8 bv = *(const bf16x8*)&L.a.rzf[(size_t)((j * 20 + 4 + ks) * 64 + lane) * 8];
            acc[j] = mfma16(av, bv, acc[j]);
          }
          #pragma unroll
          for (int j = 0; j < 2; ++j) {
            const bf16x8 bv = *(const bf16x8*)&L.a.nhf[(size_t)((j * 16 + ks) * 64 + lane) * 8];
            accn[j] = mfma16(av, bv, accn[j]);
          }
        }
        // dump gate sums to LDS exchange (C/D: col=lane&15, row=q*4+reg)
        #pragma unroll
        for (int j = 0; j < 4; ++j) {
          const int sl = j >> 1, cb = (j & 1) * 16 + col16;
          #pragma unroll
          for (int rg = 0; rg < 4; ++rg)
            L.a.ex[sl][wv * 16 + q * 4 + rg][cb] = acc[j][rg];
        }
        #pragma unroll
        for (int j = 0; j < 2; ++j) {
          const int cb = j * 16 + col16;
          #pragma unroll
          for (int rg = 0; rg < 4; ++rg) {
            L.a.ex[2][wv * 16 + q * 4 + rg][cb] = accn[j][rg];
            L.a.ex[3][wv * 16 + q * 4 + rg][cb] = acci[j][rg];
          }
        }
        __syncthreads();
        // elementwise GRU update, 4 cols/thread, 8B coherent I/O
        for (int e = tid; e < 512; e += NTHR) {
          const int row = e >> 3, cq = (e & 7) << 2;
          const int bidx = b0 + row;
          u64 hp8 = __hip_atomic_load((u64*)(hr + (size_t)bidx * HDIM + c0 + cq),
                                      __ATOMIC_RELAXED, __HIP_MEMORY_SCOPE_AGENT);
          const bf16_t* hp4 = (const bf16_t*)&hp8;
          bf16_t hw4[4], fw4[4];
          const bool v = (t < seqA[row]);
          #pragma unroll
          for (int j = 0; j < 4; ++j) {
            const int c = cq + j;
            const float gr  = L.a.ex[0][row][c] + biasA[0][c];
            const float gz  = L.a.ex[1][row][c] + biasA[1][c];
            const float gnh = L.a.ex[2][row][c] + biasA[3][c];
            const float gni = L.a.ex[3][row][c] + biasA[2][c];
            const float r = sigm(gr), zg = sigm(gz);
            const float n = tanh_f(gni + r * gnh);
            const float hp = (float)hp4[j];
            const float hnew = (1.f - zg) * n + zg * hp;
            hw4[j] = (bf16_t)(v ? hnew : hp);
            fw4[j] = (bf16_t)(v ? hnew : 0.f);
          }
          __hip_atomic_store((u64*)(hw + (size_t)bidx * HDIM + c0 + cq), *(u64*)hw4,
                             __ATOMIC_RELAXED, __HIP_MEMORY_SCOPE_AGENT);
          __hip_atomic_store((u64*)(fw + (size_t)bidx * HDIM + c0 + cq), *(u64*)fw4,
                             __ATOMIC_RELAXED, __HIP_MEMORY_SCOPE_AGENT);
        }
      }
    } else {
      if (it >= 1 && it <= TT) {           // FF1 for t = it-1
        const int t = it - 1;
        bf16_t* fr = ff + (size_t)(t & 1) * BB * HDIM;
        bf16_t* hwid = hd + (size_t)(t & 1) * BB * FFD;
        const int rB = b0 + wv * 16 + col16;
        bf16_t* pa = fr + (size_t)rB * HDIM;
        const f32x4 zz = {0.f, 0.f, 0.f, 0.f};
        f32x4 acc[4] = {zz, zz, zz, zz};
        #pragma unroll 4
        for (int ks = 0; ks < 16; ++ks) {
          const int ko = ks * 32 + q8;
          u64 fq[2];
          fq[0] = __hip_atomic_load((u64*)(pa + ko),     __ATOMIC_RELAXED, __HIP_MEMORY_SCOPE_AGENT);
          fq[1] = __hip_atomic_load((u64*)(pa + ko) + 1, __ATOMIC_RELAXED, __HIP_MEMORY_SCOPE_AGENT);
          const bf16x8 av = *(const bf16x8*)fq;
          #pragma unroll
          for (int j = 0; j < 4; ++j) {
            const bf16x8 bv = *(const bf16x8*)&L.b.w1f[(size_t)((j * 16 + ks) * 64 + lane) * 8];
            acc[j] = mfma16(av, bv, acc[j]);
          }
        }
        // relu + bias -> LDS restage -> contiguous 8B coherent stores
        #pragma unroll
        for (int j = 0; j < 4; ++j) {
          const int fc = j * 16 + col16;
          #pragma unroll
          for (int rg = 0; rg < 4; ++rg)
            L.b.st[(wv * 16 + q * 4 + rg) * 72 + fc] =
                (bf16_t)fmaxf(acc[j][rg] + b1s[fc], 0.f);
        }
        __syncthreads();
        for (int w = tid; w < 1024; w += NTHR) {
          const int r = w >> 4, cq = (w & 15) * 4;
          const u64 pk = *(const u64*)&L.b.st[r * 72 + cq];
          __hip_atomic_store((u64*)(hwid + (size_t)(b0 + r) * FFD + f0 + cq), pk,
                             __ATOMIC_RELAXED, __HIP_MEMORY_SCOPE_AGENT);
        }
      }
      if (hasC && it >= 2) {               // FF2 for t = it-2
        const int t = it - 2;
        bf16_t* hr2 = hd + (size_t)(t & 1) * BB * FFD;
        const int rC = b0c + wv * 16 + col16;
        bf16_t* pa = hr2 + (size_t)rC * FFD;
        f32x4 acc = {0.f, 0.f, 0.f, 0.f};
        #pragma unroll 4
        for (int ks = 0; ks < 32; ++ks) {
          const int ko = ks * 32 + q8;
          u64 hq[2];
          hq[0] = __hip_atomic_load((u64*)(pa + ko),     __ATOMIC_RELAXED, __HIP_MEMORY_SCOPE_AGENT);
          hq[1] = __hip_atomic_load((u64*)(pa + ko) + 1, __ATOMIC_RELAXED, __HIP_MEMORY_SCOPE_AGENT);
          const bf16x8 av = *(const bf16x8*)hq;
          const bf16x8 bv = *(const bf16x8*)&L.b.w2f[(size_t)(ks * 64 + lane) * 8];
          acc = mfma16(av, bv, acc);
        }
        #pragma unroll
        for (int rg = 0; rg < 4; ++rg) {
          const int lr = wv * 16 + q * 4 + rg;
          const int rb = b0c + lr;
          const float v = acc[rg] + b2s[col16];
          out[((size_t)rb * TT + t) * OUTD + o0 + col16] = (t < seqC[lr]) ? v : PADV;
        }
      }
    }
  }
}

extern "C" void kernel_launch(void* const* d_in, const int* in_sizes, int n_in,
                              void* d_out, int out_size, void* d_ws, size_t ws_size,
                              hipStream_t stream) {
  const float* x   = (const float*)d_in[0];
  const int*   seq = (const int*)d_in[1];
  const float* Wih = (const float*)d_in[2];
  const float* Whh = (const float*)d_in[3];
  const float* bih = (const float*)d_in[4];
  const float* bhh = (const float*)d_in[5];
  const float* W1  = (const float*)d_in[6];
  const float* b1  = (const float*)d_in[7];
  const float* W2  = (const float*)d_in[8];
  const float* b2  = (const float*)d_in[9];
  float* out = (float*)d_out;
  char* ws = (char*)d_ws;

  unsigned* bar = (unsigned*)ws;                       // 8 counters, 128B apart
  bf16_t* hb = (bf16_t*)(ws + 1024);                   // h ping-pong  2*B*H
  bf16_t* ff = hb + (size_t)2 * BB * HDIM;             // ffin ping-pong
  bf16_t* hd = ff + (size_t)2 * BB * HDIM;             // hid ping-pong 2*B*FF
  // total scratch ~4.2 MB (same envelope as R5/R7/R10)

  hipMemsetAsync(ws, 0, 1024, stream);
  void* args[] = {&x, &seq, &Wih, &Whh, &bih, &bhh, &W1, &b1, &W2, &b2,
                  &out, &hb, &ff, &hd, &bar};
  hipLaunchCooperativeKernel((void*)gru_net_kernel, dim3(NBLK), dim3(NTHR),
                             args, 0, stream);
}